// Round 9
// baseline (9353.622 us; speedup 1.0000x reference)
//
#include <hip/hip_runtime.h>

// LSTM: B=64, T=1024, D=512, H=512. Gate order i,f,g,o.
// Phase A: xW GEMM, f16 MFMA, 128x128 tile (verified r3-r6).
// Phase B: persistent scan, 16 WGs x 1024 thr = 4 row-groups(16 rows) x 4
//   quarter-slices(128 units). PROVEN protocol only (agent store + agent poll,
//   tag-in-data, two barriers) — all sc0/fence/NT experiments failed (r1/r4/r6/r8).
//   Topology change: consumer polls 3 siblings (was 15), 3 ulls/thread (was 16);
//   own quarter of h goes straight to LDS (no global round-trip).
//   Per-thread layout identical to r5: bfrag[2][16]=128 VGPR (r3 spill trap avoided).

#define B_  64
#define T_  1024
#define D_  512
#define H_  512
#define G4H 2048

typedef _Float16 half8 __attribute__((ext_vector_type(8)));
typedef _Float16 half4 __attribute__((ext_vector_type(4)));
typedef float    f32x4 __attribute__((ext_vector_type(4)));
typedef unsigned long long ull;
typedef unsigned int u32;

static __device__ __forceinline__ float sigm(float x) { return 1.f / (1.f + __expf(-x)); }
static __device__ __forceinline__ float tanh_(float x) {
    float xc = fminf(fmaxf(x, -15.f), 15.f);
    float e  = __expf(2.f * xc);
    return (e - 1.f) / (e + 1.f);
}
static __device__ __forceinline__ float lo16f(unsigned u) {
    return (float)__builtin_bit_cast(_Float16, (unsigned short)(u & 0xffffu));
}
static __device__ __forceinline__ float hi16f(unsigned u) {
    return (float)__builtin_bit_cast(_Float16, (unsigned short)(u >> 16));
}
static __device__ __forceinline__ void gload_lds16(const _Float16* g, _Float16* l) {
    __builtin_amdgcn_global_load_lds((const __attribute__((address_space(1))) u32*)g,
                                     (__attribute__((address_space(3))) u32*)l, 16, 0, 0);
}

// ---------------- init: transpose-convert [512][2048] f32 -> [2048][512] f16
__global__ void trans_w(const float* __restrict__ W, _Float16* __restrict__ WT) {
    int idx = blockIdx.x * blockDim.x + threadIdx.x;
    int total = D_ * G4H;
    int stride = gridDim.x * blockDim.x;
    for (int i = idx; i < total; i += stride) {
        int k = i >> 11;
        int n = i & (G4H - 1);
        WT[(size_t)n * D_ + k] = (_Float16)W[i];
    }
}

// ---------------- init: x f32 -> f16
__global__ void conv_x(const float* __restrict__ x, _Float16* __restrict__ xh) {
    int idx = blockIdx.x * blockDim.x + threadIdx.x;
    int total = (B_ * T_ * D_) / 4;
    int stride = gridDim.x * blockDim.x;
    const f32x4* xi = (const f32x4*)x;
    half4* xo = (half4*)xh;
    for (int i = idx; i < total; i += stride) {
        f32x4 v = xi[i];
        xo[i] = (half4){(_Float16)v.x, (_Float16)v.y, (_Float16)v.z, (_Float16)v.w};
    }
}

__global__ void zero_buf(unsigned* __restrict__ p, int n) {
    int idx = blockIdx.x * blockDim.x + threadIdx.x;
    int stride = gridDim.x * blockDim.x;
    for (int i = idx; i < n; i += stride) p[i] = 0u;
}

// ---------------- phase A (fast): 128x128 tile, f16 A via precomputed xh (verified)
__global__ __launch_bounds__(256) void gemm_xw_f16(const _Float16* __restrict__ xh,
                                                   const _Float16* __restrict__ WkT,
                                                   const float* __restrict__ bias,
                                                   _Float16* __restrict__ xw, int tbase) {
    __shared__ _Float16 As[128 * 64];   // [row][64 k] f16, XOR-swizzled (byte ^= (row&7)<<4)
    __shared__ _Float16 Bs[128 * 64];
    const int tid  = threadIdx.x;
    const int lane = tid & 63;
    const int wave = tid >> 6;
    const int l15  = lane & 15;
    const int quad = lane >> 4;
    const int b     = blockIdx.z;
    const int n0    = blockIdx.x * 128;
    const int tloc0 = blockIdx.y * 128;

    const int srow = tid >> 3;
    const int sseg = tid & 7;

    f32x4 acc[2][8];
#pragma unroll
    for (int rt = 0; rt < 2; ++rt)
#pragma unroll
        for (int ct = 0; ct < 8; ++ct) acc[rt][ct] = (f32x4){0.f, 0.f, 0.f, 0.f};

    const _Float16* abase = xh + ((size_t)b * T_ + tbase + tloc0) * D_;
    const _Float16* bbase = WkT + (size_t)n0 * D_;

    for (int kb = 0; kb < 8; ++kb) {
        __syncthreads();
#pragma unroll
        for (int q = 0; q < 4; ++q) {
            int row  = q * 32 + srow;
            int col2 = (sseg * 16) ^ ((row & 7) << 4);
            _Float16* ldst = (_Float16*)((char*)As + q * 4096 + wave * 1024);
            gload_lds16(abase + (size_t)row * D_ + kb * 64 + (col2 >> 1), ldst);
            _Float16* ldstb = (_Float16*)((char*)Bs + q * 4096 + wave * 1024);
            gload_lds16(bbase + (size_t)row * D_ + kb * 64 + (col2 >> 1), ldstb);
        }
        __syncthreads();
#pragma unroll
        for (int ks = 0; ks < 2; ++ks) {
            half8 af[2];
#pragma unroll
            for (int rt = 0; rt < 2; ++rt) {
                int row = wave * 32 + rt * 16 + l15;
                int c2  = (ks * 64 + quad * 16) ^ ((row & 7) << 4);
                af[rt] = *(const half8*)&As[row * 64 + (c2 >> 1)];
            }
#pragma unroll
            for (int ct = 0; ct < 8; ++ct) {
                int brw = ct * 16 + l15;
                int c2  = (ks * 64 + quad * 16) ^ ((brw & 7) << 4);
                half8 bf = *(const half8*)&Bs[brw * 64 + (c2 >> 1)];
                acc[0][ct] = __builtin_amdgcn_mfma_f32_16x16x32_f16(af[0], bf, acc[0][ct], 0, 0, 0);
                acc[1][ct] = __builtin_amdgcn_mfma_f32_16x16x32_f16(af[1], bf, acc[1][ct], 0, 0, 0);
            }
        }
    }
#pragma unroll
    for (int ct = 0; ct < 8; ++ct) {
        int col = n0 + ct * 16 + l15;
        float bs = bias[col];
#pragma unroll
        for (int rt = 0; rt < 2; ++rt)
#pragma unroll
            for (int r = 0; r < 4; ++r) {
                int tt = tloc0 + wave * 32 + rt * 16 + quad * 4 + r;
                xw[((size_t)tt * B_ + b) * G4H + col] = (_Float16)(acc[rt][ct][r] + bs);
            }
    }
}

// ---------------- phase A (fallback, small ws): 64x64 kernel
__global__ __launch_bounds__(256) void gemm_xw_small(const float* __restrict__ x,
                                                     const _Float16* __restrict__ WkT,
                                                     const float* __restrict__ bias,
                                                     _Float16* __restrict__ xw,
                                                     int tbase) {
    __shared__ _Float16 As[64][40];
    __shared__ _Float16 Bst[64][40];
    const int tid  = threadIdx.x;
    const int lane = tid & 63;
    const int wave = tid >> 6;
    const int l15  = lane & 15;
    const int quad = lane >> 4;
    const int b     = blockIdx.z;
    const int n0    = blockIdx.x * 64;
    const int tloc0 = blockIdx.y * 64;

    const float* xbase = x + ((size_t)b * T_ + (tbase + tloc0)) * D_;
    f32x4 acc[4];
#pragma unroll
    for (int i = 0; i < 4; ++i) acc[i] = (f32x4){0.f, 0.f, 0.f, 0.f};

    const int ai = tid >> 2, ac = tid & 3;
    const int bn = tid >> 2, bq = tid & 3;

    for (int kb = 0; kb < 16; ++kb) {
        __syncthreads();
        const float* ap = xbase + (size_t)ai * D_ + kb * 32 + ac * 8;
        f32x4 av0 = *(const f32x4*)ap;
        f32x4 av1 = *(const f32x4*)(ap + 4);
        half8 ah = { (_Float16)av0.x, (_Float16)av0.y, (_Float16)av0.z, (_Float16)av0.w,
                     (_Float16)av1.x, (_Float16)av1.y, (_Float16)av1.z, (_Float16)av1.w };
        *(half8*)&As[ai][ac * 8] = ah;
        half8 bv = *(const half8*)(WkT + (size_t)(n0 + bn) * D_ + kb * 32 + bq * 8);
        *(half8*)&Bst[bn][bq * 8] = bv;
        __syncthreads();

        half8 afrag = *(const half8*)&As[16 * wave + l15][quad * 8];
#pragma unroll
        for (int nt = 0; nt < 4; ++nt) {
            half8 bfrag = *(const half8*)&Bst[nt * 16 + l15][quad * 8];
            acc[nt] = __builtin_amdgcn_mfma_f32_16x16x32_f16(afrag, bfrag, acc[nt], 0, 0, 0);
        }
    }
#pragma unroll
    for (int nt = 0; nt < 4; ++nt)
#pragma unroll
        for (int r = 0; r < 4; ++r) {
            int tt  = tloc0 + 16 * wave + quad * 4 + r;
            int col = n0 + nt * 16 + l15;
            xw[((size_t)tt * B_ + b) * G4H + col] = (_Float16)(acc[nt][r] + bias[col]);
        }
}

// ---------------- phase B: persistent scan, quarter-slice topology
// 16 WGs x 1024 thr. WG w: group g=w>>2 (rows g*16..+15), quarter q=w&3
// (units q*128..+127). Wave v (16 waves): MFMA role u=v>>1 (uc-tile), hf=v&1
// (gates 2hf,2hf+1); activation role row rho=v, lane jj covers units 2jj,2jj+1.
// hbuf: 3 slots x [64][512] tagged dwords (lo16 = h f16, hi16 = step+1).
// Own quarter of h -> LDS directly; only 3 sibling quarters via global (3 ull/thr).
__global__ __launch_bounds__(1024, 1) void lstm_scan(const _Float16* __restrict__ xw,
                                                     const _Float16* __restrict__ WrT,
                                                     unsigned* __restrict__ hbuf,
                                                     float* __restrict__ cio,
                                                     float* __restrict__ out,
                                                     int t0, int t1) {
    const int w    = blockIdx.x;
    const int g    = w >> 2;
    const int q    = w & 3;
    const int tid  = threadIdx.x;
    const int lane = tid & 63;
    const int wave = tid >> 6;
    const int l15  = lane & 15;
    const int quad = lane >> 4;
    const int u    = wave >> 1;       // uc-tile 0..7
    const int hf   = wave & 1;        // gate-pair: 0 -> i,f ; 1 -> g,o

    // B-frags: wave covers cols (2hf+ct)*512 + q*128 + u*16 + l15, ct=0,1.
    // bfrag[2][16] = 128 VGPR (r5-proven pressure, no spill).
    half8 bfrag[2][16];
#pragma unroll
    for (int ct = 0; ct < 2; ++ct) {
        const int col = (2 * hf + ct) * H_ + q * 128 + u * 16 + l15;
        const _Float16* wp = WrT + (size_t)col * D_;
#pragma unroll
        for (int kt = 0; kt < 16; ++kt)
            bfrag[ct][kt] = *(const half8*)(wp + kt * 32 + quad * 8);
    }

    const int rho  = wave;            // activation row (0..15)
    const int jj   = lane;            // unit-pair in quarter (0..63)
    const int brow = g * 16 + rho;
    const int un0  = q * 128 + 2 * jj;
    float c0 = 0.f, c1 = 0.f;
    if (t0 != 0) {
        c0 = cio[(size_t)brow * H_ + un0];
        c1 = cio[(size_t)brow * H_ + un0 + 1];
    }

    __shared__ _Float16 hS[16][520];     // full group h (K=512), r5 geometry
    __shared__ float    zS[16][4][136];  // z for this WG's 128 units x 4 gates

    const size_t slotSz = (size_t)B_ * H_;   // dwords per slot

    // sibling poll mapping: 3 ull indices in [0,256) skipping own quarter ups.
    int upm[3];
#pragma unroll
    for (int m = 0; m < 3; ++m) {
        int idx = jj + 64 * m;                       // [0,192)
        upm[m] = idx + ((idx >= q * 64) ? 64 : 0);   // skip own [q*64, q*64+64)
    }

    for (int t = t0; t < t1; ++t) {
        // xw prefetch: 4 f16-pair dwords, one per gate, for units un0,un0+1
        const unsigned* xwd = (const unsigned*)(xw + ((size_t)(t - t0) * B_ + brow) * G4H);
        const int dbase = q * 64 + jj;
        unsigned xwi = xwd[0 * 256 + dbase];
        unsigned xwf = xwd[1 * 256 + dbase];
        unsigned xwg = xwd[2 * 256 + dbase];
        unsigned xwo = xwd[3 * 256 + dbase];

        if (t > 0) {
            const ull* srcb = (const ull*)(hbuf + (size_t)((t - 1) % 3) * slotSz)
                              + (size_t)brow * 256;
            const unsigned tgt = (unsigned)(t & 0xffff);
            const ull expect = ((ull)tgt << 16) | ((ull)tgt << 48);
            ull v0 = 0, v1 = 0, v2 = 0;
            int guard = 0;
            while (true) {
                v0 = __hip_atomic_load(srcb + upm[0], __ATOMIC_RELAXED, __HIP_MEMORY_SCOPE_AGENT);
                v1 = __hip_atomic_load(srcb + upm[1], __ATOMIC_RELAXED, __HIP_MEMORY_SCOPE_AGENT);
                v2 = __hip_atomic_load(srcb + upm[2], __ATOMIC_RELAXED, __HIP_MEMORY_SCOPE_AGENT);
                ull diff = ((v0 ^ expect) | (v1 ^ expect) | (v2 ^ expect))
                           & 0xffff0000ffff0000ull;
                if (diff == 0) break;
                if (++guard > 8192) break;   // bailout: visible failure, not a hang
            }
            // first step of a resumed chunk: own quarter not in LDS yet — fetch it
            if (t == t0) {
                ull vo; int gd = 0;
                do {
                    vo = __hip_atomic_load(srcb + (q * 64 + jj),
                                           __ATOMIC_RELAXED, __HIP_MEMORY_SCOPE_AGENT);
                } while (((vo ^ expect) & 0xffff0000ffff0000ull) && ++gd < 8192);
                *(unsigned*)&hS[rho][2 * (q * 64 + jj)] =
                    (unsigned)(vo & 0xffffu) | ((unsigned)(vo >> 32) << 16);
            }
            // strip tags, stage sibling quarters
#pragma unroll
            for (int m = 0; m < 3; ++m) {
                ull vk = (m == 0) ? v0 : (m == 1) ? v1 : v2;
                *(unsigned*)&hS[rho][2 * upm[m]] =
                    (unsigned)(vk & 0xffffu) | ((unsigned)(vk >> 32) << 16);
            }
        }
        __syncthreads();   // BARRIER1: hS complete (own written prev step, siblings staged)

        f32x4 a0 = {0.f,0.f,0.f,0.f}, a1 = a0, b0 = a0, b1 = a0;
        if (t > 0) {
#pragma unroll
            for (int kt = 0; kt < 16; kt += 2) {
                half8 af0 = *(const half8*)&hS[l15][kt * 32 + quad * 8];
                half8 af1 = *(const half8*)&hS[l15][(kt + 1) * 32 + quad * 8];
                a0 = __builtin_amdgcn_mfma_f32_16x16x32_f16(af0, bfrag[0][kt],     a0, 0, 0, 0);
                a1 = __builtin_amdgcn_mfma_f32_16x16x32_f16(af0, bfrag[1][kt],     a1, 0, 0, 0);
                b0 = __builtin_amdgcn_mfma_f32_16x16x32_f16(af1, bfrag[0][kt + 1], b0, 0, 0, 0);
                b1 = __builtin_amdgcn_mfma_f32_16x16x32_f16(af1, bfrag[1][kt + 1], b1, 0, 0, 0);
            }
        }
        f32x4 z0 = a0 + b0, z1 = a1 + b1;
#pragma unroll
        for (int r = 0; r < 4; ++r) {
            zS[quad * 4 + r][2 * hf][u * 16 + l15]     = z0[r];
            zS[quad * 4 + r][2 * hf + 1][u * 16 + l15] = z1[r];
        }
        __syncthreads();   // BARRIER2: zS ready (also fences hS reads vs post-act writes)

        float zi0 = zS[rho][0][2*jj] + lo16f(xwi), zi1 = zS[rho][0][2*jj+1] + hi16f(xwi);
        float zf0 = zS[rho][1][2*jj] + lo16f(xwf), zf1 = zS[rho][1][2*jj+1] + hi16f(xwf);
        float zg0 = zS[rho][2][2*jj] + lo16f(xwg), zg1 = zS[rho][2][2*jj+1] + hi16f(xwg);
        float zo0 = zS[rho][3][2*jj] + lo16f(xwo), zo1 = zS[rho][3][2*jj+1] + hi16f(xwo);

        c0 = sigm(zf0) * c0 + sigm(zi0) * tanh_(zg0);
        c1 = sigm(zf1) * c1 + sigm(zi1) * tanh_(zg1);
        float h0 = sigm(zo0) * tanh_(c0);
        float h1 = sigm(zo1) * tanh_(c1);

        // own h -> LDS directly (no global round-trip for own quarter)
        unsigned h0b = (unsigned)__builtin_bit_cast(unsigned short, (_Float16)h0);
        unsigned h1b = (unsigned)__builtin_bit_cast(unsigned short, (_Float16)h1);
        *(unsigned*)&hS[rho][2 * (q * 64 + jj)] = h0b | (h1b << 16);

        // tagged publish for siblings: ONE 8B relaxed agent store (proven protocol)
        const unsigned tagw = ((unsigned)((t + 1) & 0xffff)) << 16;
        ull wv = (ull)(h0b | tagw) | (((ull)(h1b | tagw)) << 32);
        __hip_atomic_store((ull*)(hbuf + (size_t)(t % 3) * slotSz)
                               + (size_t)brow * 256 + (q * 64 + jj),
                           wv, __ATOMIC_RELAXED, __HIP_MEMORY_SCOPE_AGENT);

        if (t == T_ - 1) {
            out[(size_t)brow * H_ + un0]     = h0;
            out[(size_t)brow * H_ + un0 + 1] = h1;
        }
    }
    cio[(size_t)brow * H_ + un0]     = c0;
    cio[(size_t)brow * H_ + un0 + 1] = c1;
}

// ---------------- launch
extern "C" void kernel_launch(void* const* d_in, const int* in_sizes, int n_in,
                              void* d_out, int out_size, void* d_ws, size_t ws_size,
                              hipStream_t stream) {
    (void)in_sizes; (void)n_in;
    const float* x    = (const float*)d_in[0];
    const float* Wk   = (const float*)d_in[1];
    const float* Wr   = (const float*)d_in[2];
    const float* bias = (const float*)d_in[3];
    float* out = (float*)d_out;

    char* ws = (char*)d_ws;
    _Float16* WkT  = (_Float16*)(ws + 1024);                      // 2 MB
    _Float16* WrT  = (_Float16*)(ws + 1024 + 2097152);            // 2 MB
    unsigned* hbuf = (unsigned*)(ws + 1024 + 2 * 2097152);        // 384 KB (3 slots)
    float*    cio  = (float*)(ws + 1024 + 2 * 2097152 + 393216);  // 128 KB
    const size_t fixed   = 1024 + 2 * 2097152 + 393216 + 131072;
    const size_t xhBytes = (size_t)B_ * T_ * D_ * 2;              // 64 MB
    const size_t perT    = (size_t)B_ * G4H * 2;                  // 256 KB per timestep

    size_t avail = (ws_size > fixed) ? ws_size - fixed : 0;
    bool use_xh = avail >= xhBytes + 128 * perT;
    _Float16* xh = (_Float16*)(ws + fixed);
    _Float16* xw = (_Float16*)(ws + fixed + (use_xh ? xhBytes : 0));

    int ct = 0;
    if (use_xh) {
        const int cands[4] = {1024, 512, 256, 128};
        size_t av2 = avail - xhBytes;
        for (int i = 0; i < 4; ++i)
            if ((size_t)cands[i] * perT <= av2) { ct = cands[i]; break; }
    } else {
        const int cands[5] = {1024, 512, 256, 128, 64};
        for (int i = 0; i < 5; ++i)
            if ((size_t)cands[i] * perT <= avail) { ct = cands[i]; break; }
    }
    if (ct == 0) {
        hipMemsetAsync(d_out, 0, (size_t)out_size * 4, stream);
        return;
    }

    zero_buf<<<96, 256, 0, stream>>>(hbuf, 3 * B_ * H_);
    trans_w<<<512, 256, 0, stream>>>(Wk, WkT);
    trans_w<<<512, 256, 0, stream>>>(Wr, WrT);
    if (use_xh) conv_x<<<2048, 256, 0, stream>>>(x, xh);

    for (int t0 = 0; t0 < T_; t0 += ct) {
        if (use_xh)
            gemm_xw_f16<<<dim3(16, ct / 128, B_), 256, 0, stream>>>(xh, WkT, bias, xw, t0);
        else
            gemm_xw_small<<<dim3(32, ct / 64, B_), 256, 0, stream>>>(x, WkT, bias, xw, t0);
        lstm_scan<<<16, 1024, 0, stream>>>(xw, WrT, hbuf, cio, out, t0, t0 + ct);
    }
}

// Round 10
// 3384.379 us; speedup vs baseline: 2.7638x; 2.7638x over previous
//
#include <hip/hip_runtime.h>

// LSTM: B=64, T=1024, D=512, H=512. Gate order i,f,g,o.
// Phase A: xW GEMM, f16 MFMA, 128x128 tile (verified r3-r6).
// Phase B: persistent scan — r5-PROVEN topology (64 WGs = 4 row-groups(16 rows)
//   x 16 slices(32 units), tag-in-data agent publish + agent poll, two barriers)
//   refined to 512 thr / 8 waves per WG:
//   - wave v = (gate, col-half): bfrag[16] = 64 VGPR (away from spill cliff;
//     r3/r9 lesson: compiler spills big arrays when occupancy heuristic bites)
//   - poll 8 ulls/thread (was 16) -> shorter rounds, finer detection
//   - 1 unit/thread activation; 4B tagged-dword publish (pair tags still checked)
//   NO protocol experiments (sc0/fence/NT all failed: r1/r4/r6/r8).

#define B_  64
#define T_  1024
#define D_  512
#define H_  512
#define G4H 2048

typedef _Float16 half8 __attribute__((ext_vector_type(8)));
typedef _Float16 half4 __attribute__((ext_vector_type(4)));
typedef float    f32x4 __attribute__((ext_vector_type(4)));
typedef unsigned long long ull;
typedef unsigned int u32;

static __device__ __forceinline__ float sigm(float x) { return 1.f / (1.f + __expf(-x)); }
static __device__ __forceinline__ float tanh_(float x) {
    float xc = fminf(fmaxf(x, -15.f), 15.f);
    float e  = __expf(2.f * xc);
    return (e - 1.f) / (e + 1.f);
}
static __device__ __forceinline__ void gload_lds16(const _Float16* g, _Float16* l) {
    __builtin_amdgcn_global_load_lds((const __attribute__((address_space(1))) u32*)g,
                                     (__attribute__((address_space(3))) u32*)l, 16, 0, 0);
}

// ---------------- init: transpose-convert [512][2048] f32 -> [2048][512] f16
__global__ void trans_w(const float* __restrict__ W, _Float16* __restrict__ WT) {
    int idx = blockIdx.x * blockDim.x + threadIdx.x;
    int total = D_ * G4H;
    int stride = gridDim.x * blockDim.x;
    for (int i = idx; i < total; i += stride) {
        int k = i >> 11;
        int n = i & (G4H - 1);
        WT[(size_t)n * D_ + k] = (_Float16)W[i];
    }
}

// ---------------- init: x f32 -> f16
__global__ void conv_x(const float* __restrict__ x, _Float16* __restrict__ xh) {
    int idx = blockIdx.x * blockDim.x + threadIdx.x;
    int total = (B_ * T_ * D_) / 4;
    int stride = gridDim.x * blockDim.x;
    const f32x4* xi = (const f32x4*)x;
    half4* xo = (half4*)xh;
    for (int i = idx; i < total; i += stride) {
        f32x4 v = xi[i];
        xo[i] = (half4){(_Float16)v.x, (_Float16)v.y, (_Float16)v.z, (_Float16)v.w};
    }
}

__global__ void zero_buf(unsigned* __restrict__ p, int n) {
    int idx = blockIdx.x * blockDim.x + threadIdx.x;
    int stride = gridDim.x * blockDim.x;
    for (int i = idx; i < n; i += stride) p[i] = 0u;
}

// ---------------- phase A (fast): 128x128 tile, f16 A via precomputed xh (verified)
__global__ __launch_bounds__(256) void gemm_xw_f16(const _Float16* __restrict__ xh,
                                                   const _Float16* __restrict__ WkT,
                                                   const float* __restrict__ bias,
                                                   _Float16* __restrict__ xw, int tbase) {
    __shared__ _Float16 As[128 * 64];   // [row][64 k] f16, XOR-swizzled (byte ^= (row&7)<<4)
    __shared__ _Float16 Bs[128 * 64];
    const int tid  = threadIdx.x;
    const int lane = tid & 63;
    const int wave = tid >> 6;
    const int l15  = lane & 15;
    const int quad = lane >> 4;
    const int b     = blockIdx.z;
    const int n0    = blockIdx.x * 128;
    const int tloc0 = blockIdx.y * 128;

    const int srow = tid >> 3;
    const int sseg = tid & 7;

    f32x4 acc[2][8];
#pragma unroll
    for (int rt = 0; rt < 2; ++rt)
#pragma unroll
        for (int ct = 0; ct < 8; ++ct) acc[rt][ct] = (f32x4){0.f, 0.f, 0.f, 0.f};

    const _Float16* abase = xh + ((size_t)b * T_ + tbase + tloc0) * D_;
    const _Float16* bbase = WkT + (size_t)n0 * D_;

    for (int kb = 0; kb < 8; ++kb) {
        __syncthreads();
#pragma unroll
        for (int q = 0; q < 4; ++q) {
            int row  = q * 32 + srow;
            int col2 = (sseg * 16) ^ ((row & 7) << 4);
            _Float16* ldst = (_Float16*)((char*)As + q * 4096 + wave * 1024);
            gload_lds16(abase + (size_t)row * D_ + kb * 64 + (col2 >> 1), ldst);
            _Float16* ldstb = (_Float16*)((char*)Bs + q * 4096 + wave * 1024);
            gload_lds16(bbase + (size_t)row * D_ + kb * 64 + (col2 >> 1), ldstb);
        }
        __syncthreads();
#pragma unroll
        for (int ks = 0; ks < 2; ++ks) {
            half8 af[2];
#pragma unroll
            for (int rt = 0; rt < 2; ++rt) {
                int row = wave * 32 + rt * 16 + l15;
                int c2  = (ks * 64 + quad * 16) ^ ((row & 7) << 4);
                af[rt] = *(const half8*)&As[row * 64 + (c2 >> 1)];
            }
#pragma unroll
            for (int ct = 0; ct < 8; ++ct) {
                int brw = ct * 16 + l15;
                int c2  = (ks * 64 + quad * 16) ^ ((brw & 7) << 4);
                half8 bf = *(const half8*)&Bs[brw * 64 + (c2 >> 1)];
                acc[0][ct] = __builtin_amdgcn_mfma_f32_16x16x32_f16(af[0], bf, acc[0][ct], 0, 0, 0);
                acc[1][ct] = __builtin_amdgcn_mfma_f32_16x16x32_f16(af[1], bf, acc[1][ct], 0, 0, 0);
            }
        }
    }
#pragma unroll
    for (int ct = 0; ct < 8; ++ct) {
        int col = n0 + ct * 16 + l15;
        float bs = bias[col];
#pragma unroll
        for (int rt = 0; rt < 2; ++rt)
#pragma unroll
            for (int r = 0; r < 4; ++r) {
                int tt = tloc0 + wave * 32 + rt * 16 + quad * 4 + r;
                xw[((size_t)tt * B_ + b) * G4H + col] = (_Float16)(acc[rt][ct][r] + bs);
            }
    }
}

// ---------------- phase A (fallback, small ws): 64x64 kernel
__global__ __launch_bounds__(256) void gemm_xw_small(const float* __restrict__ x,
                                                     const _Float16* __restrict__ WkT,
                                                     const float* __restrict__ bias,
                                                     _Float16* __restrict__ xw,
                                                     int tbase) {
    __shared__ _Float16 As[64][40];
    __shared__ _Float16 Bst[64][40];
    const int tid  = threadIdx.x;
    const int lane = tid & 63;
    const int wave = tid >> 6;
    const int l15  = lane & 15;
    const int quad = lane >> 4;
    const int b     = blockIdx.z;
    const int n0    = blockIdx.x * 64;
    const int tloc0 = blockIdx.y * 64;

    const float* xbase = x + ((size_t)b * T_ + (tbase + tloc0)) * D_;
    f32x4 acc[4];
#pragma unroll
    for (int i = 0; i < 4; ++i) acc[i] = (f32x4){0.f, 0.f, 0.f, 0.f};

    const int ai = tid >> 2, ac = tid & 3;
    const int bn = tid >> 2, bq = tid & 3;

    for (int kb = 0; kb < 16; ++kb) {
        __syncthreads();
        const float* ap = xbase + (size_t)ai * D_ + kb * 32 + ac * 8;
        f32x4 av0 = *(const f32x4*)ap;
        f32x4 av1 = *(const f32x4*)(ap + 4);
        half8 ah = { (_Float16)av0.x, (_Float16)av0.y, (_Float16)av0.z, (_Float16)av0.w,
                     (_Float16)av1.x, (_Float16)av1.y, (_Float16)av1.z, (_Float16)av1.w };
        *(half8*)&As[ai][ac * 8] = ah;
        half8 bv = *(const half8*)(WkT + (size_t)(n0 + bn) * D_ + kb * 32 + bq * 8);
        *(half8*)&Bst[bn][bq * 8] = bv;
        __syncthreads();

        half8 afrag = *(const half8*)&As[16 * wave + l15][quad * 8];
#pragma unroll
        for (int nt = 0; nt < 4; ++nt) {
            half8 bfrag = *(const half8*)&Bst[nt * 16 + l15][quad * 8];
            acc[nt] = __builtin_amdgcn_mfma_f32_16x16x32_f16(afrag, bfrag, acc[nt], 0, 0, 0);
        }
    }
#pragma unroll
    for (int nt = 0; nt < 4; ++nt)
#pragma unroll
        for (int r = 0; r < 4; ++r) {
            int tt  = tloc0 + 16 * wave + quad * 4 + r;
            int col = n0 + nt * 16 + l15;
            xw[((size_t)tt * B_ + b) * G4H + col] = (_Float16)(acc[nt][r] + bias[col]);
        }
}

// ---------------- phase B: persistent scan (r5 topology, 512 thr / 8 waves)
// 64 WGs. WG w: group g=w&3 (rows g*16..+15), slice s=w>>2 (units s*32..+31).
// Wave v: gate gt=v>>1, col-half ctw=v&1 -> cols gt*512 + u0 + ctw*16 + 0..15.
// hbuf: 3 slots x [64][512] tagged dwords (lo16 = h f16, hi16 = step+1).
__global__ __launch_bounds__(512, 1) void lstm_scan(const _Float16* __restrict__ xw,
                                                    const _Float16* __restrict__ WrT,
                                                    unsigned* __restrict__ hbuf,
                                                    float* __restrict__ cio,
                                                    float* __restrict__ out,
                                                    int t0, int t1) {
    const int w    = blockIdx.x;
    const int g    = w & 3;
    const int s    = w >> 2;
    const int u0   = s * 32;
    const int tid  = threadIdx.x;
    const int lane = tid & 63;
    const int wave = tid >> 6;        // 0..7
    const int l15  = lane & 15;
    const int quad = lane >> 4;
    const int gt   = wave >> 1;       // gate 0..3
    const int ctw  = wave & 1;        // col-half 0..1

    // B-frag: ONE col tile per wave -> 64 VGPR (half of r5's proven 128).
    half8 bfrag[16];
    {
        const int col = gt * H_ + u0 + ctw * 16 + l15;
        const _Float16* wp = WrT + (size_t)col * D_;
#pragma unroll
        for (int kt = 0; kt < 16; ++kt)
            bfrag[kt] = *(const half8*)(wp + kt * 32 + quad * 8);
    }

    const int rho  = tid >> 5;        // batch-row in group (0..15)
    const int uu   = tid & 31;        // unit within slice (0..31)
    const int brow = g * 16 + rho;
    const int un   = u0 + uu;
    float c = 0.f;
    if (t0 != 0) c = cio[(size_t)brow * H_ + un];

    __shared__ _Float16 hS[16][520];      // group h tile, pad 8 f16 (r5 geometry)
    __shared__ float    zS[16][4][35];    // z exchange (pad 35: 2-way banks)

    const size_t slotSz = (size_t)B_ * H_;   // dwords per slot
    // poll role: pair-column pp (0..255) x row-half rh (0..1, rows rh*8..+7)
    const int pp = tid & 255;
    const int rh = tid >> 8;

    for (int t = t0; t < t1; ++t) {
        // xw prefetch: 4 scalar f16 (one per gate) for this thread's unit
        const _Float16* xwp = xw + ((size_t)(t - t0) * B_ + brow) * G4H + un;
        float xi_ = (float)xwp[0 * 512];
        float xf_ = (float)xwp[1 * 512];
        float xg_ = (float)xwp[2 * 512];
        float xo_ = (float)xwp[3 * 512];

        if (t > 0) {
            // 8 tagged ulls: pair pp, rows g*16+rh*8 .. +7 (one producer WG: (g, pp>>4))
            const ull* src = (const ull*)(hbuf + (size_t)((t - 1) % 3) * slotSz)
                             + (size_t)(g * 16 + rh * 8) * 256 + pp;
            const unsigned tgt = (unsigned)(t & 0xffff);
            const ull expect = ((ull)tgt << 16) | ((ull)tgt << 48);
            ull v[8];
            int guard = 0;
            while (true) {
                ull diff = 0;
#pragma unroll
                for (int k = 0; k < 8; ++k)
                    v[k] = __hip_atomic_load(src + (size_t)k * 256,
                                             __ATOMIC_RELAXED, __HIP_MEMORY_SCOPE_AGENT);
#pragma unroll
                for (int k = 0; k < 8; ++k)
                    diff |= (v[k] ^ expect) & 0xffff0000ffff0000ull;
                if (diff == 0) break;
                if (++guard > 8192) break;   // bailout: visible failure, not a hang
            }
            // strip tags, pack 2 f16 -> dword, stage to LDS
#pragma unroll
            for (int k = 0; k < 8; ++k) {
                unsigned p = (unsigned)(v[k] & 0xffffu) | (((unsigned)(v[k] >> 32)) << 16);
                *(unsigned*)&hS[rh * 8 + k][2 * pp] = p;
            }
        }
        __syncthreads();   // BARRIER1: hS staged (also protects hS vs prev-step readers)

        f32x4 a = {0.f, 0.f, 0.f, 0.f};
        if (t > 0) {
#pragma unroll
            for (int kt = 0; kt < 16; ++kt) {
                half8 af = *(const half8*)&hS[l15][kt * 32 + quad * 8];
                a = __builtin_amdgcn_mfma_f32_16x16x32_f16(af, bfrag[kt], a, 0, 0, 0);
            }
        }
#pragma unroll
        for (int r = 0; r < 4; ++r)
            zS[quad * 4 + r][gt][ctw * 16 + l15] = a[r];
        __syncthreads();   // BARRIER2: zS ready

        float zi = zS[rho][0][uu] + xi_;
        float zf = zS[rho][1][uu] + xf_;
        float zg = zS[rho][2][uu] + xg_;
        float zo = zS[rho][3][uu] + xo_;

        c = sigm(zf) * c + sigm(zi) * tanh_(zg);
        float h = sigm(zo) * tanh_(c);

        // tagged publish: ONE 4B relaxed agent store (pair tags still both checked)
        unsigned d = (unsigned)__builtin_bit_cast(unsigned short, (_Float16)h)
                   | (((unsigned)((t + 1) & 0xffff)) << 16);
        __hip_atomic_store(hbuf + (size_t)(t % 3) * slotSz + (size_t)brow * H_ + un,
                           d, __ATOMIC_RELAXED, __HIP_MEMORY_SCOPE_AGENT);

        if (t == T_ - 1) out[(size_t)brow * H_ + un] = h;
    }
    cio[(size_t)brow * H_ + un] = c;
}

// ---------------- launch
extern "C" void kernel_launch(void* const* d_in, const int* in_sizes, int n_in,
                              void* d_out, int out_size, void* d_ws, size_t ws_size,
                              hipStream_t stream) {
    (void)in_sizes; (void)n_in;
    const float* x    = (const float*)d_in[0];
    const float* Wk   = (const float*)d_in[1];
    const float* Wr   = (const float*)d_in[2];
    const float* bias = (const float*)d_in[3];
    float* out = (float*)d_out;

    char* ws = (char*)d_ws;
    _Float16* WkT  = (_Float16*)(ws + 1024);                      // 2 MB
    _Float16* WrT  = (_Float16*)(ws + 1024 + 2097152);            // 2 MB
    unsigned* hbuf = (unsigned*)(ws + 1024 + 2 * 2097152);        // 384 KB (3 slots)
    float*    cio  = (float*)(ws + 1024 + 2 * 2097152 + 393216);  // 128 KB
    const size_t fixed   = 1024 + 2 * 2097152 + 393216 + 131072;
    const size_t xhBytes = (size_t)B_ * T_ * D_ * 2;              // 64 MB
    const size_t perT    = (size_t)B_ * G4H * 2;                  // 256 KB per timestep

    size_t avail = (ws_size > fixed) ? ws_size - fixed : 0;
    bool use_xh = avail >= xhBytes + 128 * perT;
    _Float16* xh = (_Float16*)(ws + fixed);
    _Float16* xw = (_Float16*)(ws + fixed + (use_xh ? xhBytes : 0));

    int ct = 0;
    if (use_xh) {
        const int cands[4] = {1024, 512, 256, 128};
        size_t av2 = avail - xhBytes;
        for (int i = 0; i < 4; ++i)
            if ((size_t)cands[i] * perT <= av2) { ct = cands[i]; break; }
    } else {
        const int cands[5] = {1024, 512, 256, 128, 64};
        for (int i = 0; i < 5; ++i)
            if ((size_t)cands[i] * perT <= avail) { ct = cands[i]; break; }
    }
    if (ct == 0) {
        hipMemsetAsync(d_out, 0, (size_t)out_size * 4, stream);
        return;
    }

    zero_buf<<<96, 256, 0, stream>>>(hbuf, 3 * B_ * H_);
    trans_w<<<512, 256, 0, stream>>>(Wk, WkT);
    trans_w<<<512, 256, 0, stream>>>(Wr, WrT);
    if (use_xh) conv_x<<<2048, 256, 0, stream>>>(x, xh);

    for (int t0 = 0; t0 < T_; t0 += ct) {
        if (use_xh)
            gemm_xw_f16<<<dim3(16, ct / 128, B_), 256, 0, stream>>>(xh, WkT, bias, xw, t0);
        else
            gemm_xw_small<<<dim3(32, ct / 64, B_), 256, 0, stream>>>(x, WkT, bias, xw, t0);
        lstm_scan<<<64, 512, 0, stream>>>(xw, WrT, hbuf, cio, out, t0, t0 + ct);
    }
}

// Round 11
// 3276.333 us; speedup vs baseline: 2.8549x; 1.0330x over previous
//
#include <hip/hip_runtime.h>

// LSTM: B=64, T=1024, D=512, H=512. Gate order i,f,g,o.
// FUSED producer/consumer kernel: 256 WGs x 256 thr.
//   WGs 0..63:  scan role — VERBATIM r5 scan (best verified: 2788us, VGPR 132):
//     4 row-groups(16 rows) x 16 slices(32 units), tag-in-data agent publish,
//     16-ull agent poll, two barriers. Only changes: absolute t (single launch),
//     per-chunk gate (1 per 128 steps): tid0 spins chunkdone, barrier, acquire fence.
//   WGs 64..255: producer role — gemm_xw_f16 tile body (verified r3-r6), tiles in
//     chunk order; per tile: stores -> __syncthreads (vmcnt drain) -> tid0
//     RELEASE fetch_add chunkdone[chunk] (L2 writeback => xw agent-visible).
//   Rationale: scan is at the IC-latency floor (~2.7us/step, 6 failed protocol
//   experiments r1/r4/r6/r8/r9/r10); remaining win = hide GEMM's ~250us serial
//   time inside the scan's 95%-idle CUs. Fallback: r5 chunked path if ws small.

#define B_  64
#define T_  1024
#define D_  512
#define H_  512
#define G4H 2048
#define NPROD 192
#define TILES_TOTAL 8192
#define TILES_PER_CHUNK 1024

typedef _Float16 half8 __attribute__((ext_vector_type(8)));
typedef _Float16 half4 __attribute__((ext_vector_type(4)));
typedef float    f32x4 __attribute__((ext_vector_type(4)));
typedef unsigned long long ull;
typedef unsigned int u32;

static __device__ __forceinline__ float sigm(float x) { return 1.f / (1.f + __expf(-x)); }
static __device__ __forceinline__ float tanh_(float x) {
    float xc = fminf(fmaxf(x, -15.f), 15.f);
    float e  = __expf(2.f * xc);
    return (e - 1.f) / (e + 1.f);
}
static __device__ __forceinline__ float lo16f(unsigned u) {
    return (float)__builtin_bit_cast(_Float16, (unsigned short)(u & 0xffffu));
}
static __device__ __forceinline__ float hi16f(unsigned u) {
    return (float)__builtin_bit_cast(_Float16, (unsigned short)(u >> 16));
}
static __device__ __forceinline__ void gload_lds16(const _Float16* g, _Float16* l) {
    __builtin_amdgcn_global_load_lds((const __attribute__((address_space(1))) u32*)g,
                                     (__attribute__((address_space(3))) u32*)l, 16, 0, 0);
}

// ---------------- init: transpose-convert [512][2048] f32 -> [2048][512] f16
__global__ void trans_w(const float* __restrict__ W, _Float16* __restrict__ WT) {
    int idx = blockIdx.x * blockDim.x + threadIdx.x;
    int total = D_ * G4H;
    int stride = gridDim.x * blockDim.x;
    for (int i = idx; i < total; i += stride) {
        int k = i >> 11;
        int n = i & (G4H - 1);
        WT[(size_t)n * D_ + k] = (_Float16)W[i];
    }
}

// ---------------- init: x f32 -> f16
__global__ void conv_x(const float* __restrict__ x, _Float16* __restrict__ xh) {
    int idx = blockIdx.x * blockDim.x + threadIdx.x;
    int total = (B_ * T_ * D_) / 4;
    int stride = gridDim.x * blockDim.x;
    const f32x4* xi = (const f32x4*)x;
    half4* xo = (half4*)xh;
    for (int i = idx; i < total; i += stride) {
        f32x4 v = xi[i];
        xo[i] = (half4){(_Float16)v.x, (_Float16)v.y, (_Float16)v.z, (_Float16)v.w};
    }
}

__global__ void zero_buf(unsigned* __restrict__ p, int n) {
    int idx = blockIdx.x * blockDim.x + threadIdx.x;
    int stride = gridDim.x * blockDim.x;
    for (int i = idx; i < n; i += stride) p[i] = 0u;
}

// ---------------- FUSED kernel
__global__ __launch_bounds__(256, 1) void lstm_fused(const _Float16* __restrict__ xh,
                                                     const _Float16* __restrict__ WkT,
                                                     const float* __restrict__ bias,
                                                     _Float16* __restrict__ xw,
                                                     const _Float16* __restrict__ WrT,
                                                     unsigned* __restrict__ hbuf,
                                                     float* __restrict__ out,
                                                     unsigned* __restrict__ ctrl) {
    // LDS for both roles (statically summed: 32K + ~26K = 58K, fine)
    __shared__ _Float16 As[128 * 64];
    __shared__ _Float16 Bs[128 * 64];
    __shared__ _Float16 hS[16][520];
    __shared__ float    zS[16][4][34];

    const int tid  = threadIdx.x;
    const int lane = tid & 63;
    const int wave = tid >> 6;
    const int l15  = lane & 15;
    const int quad = lane >> 4;

    if (blockIdx.x >= 64) {
        // ================= producer role: gemm tiles in chunk order =================
        const int p = blockIdx.x - 64;
        const int srow = tid >> 3;
        const int sseg = tid & 7;
        for (int tau = p; tau < TILES_TOTAL; tau += NPROD) {
            const int chunk = tau >> 10;
            const int loc   = tau & 1023;
            const int n0    = (loc & 15) * 128;
            const int b     = loc >> 4;
            const int tb    = chunk * 128;      // absolute first step of tile rows

            f32x4 acc[2][8];
#pragma unroll
            for (int rt = 0; rt < 2; ++rt)
#pragma unroll
                for (int ct = 0; ct < 8; ++ct) acc[rt][ct] = (f32x4){0.f, 0.f, 0.f, 0.f};

            const _Float16* abase = xh + ((size_t)b * T_ + tb) * D_;
            const _Float16* bbase = WkT + (size_t)n0 * D_;

            for (int kb = 0; kb < 8; ++kb) {
                __syncthreads();
#pragma unroll
                for (int q = 0; q < 4; ++q) {
                    int row  = q * 32 + srow;
                    int col2 = (sseg * 16) ^ ((row & 7) << 4);
                    _Float16* ldst = (_Float16*)((char*)As + q * 4096 + wave * 1024);
                    gload_lds16(abase + (size_t)row * D_ + kb * 64 + (col2 >> 1), ldst);
                    _Float16* ldstb = (_Float16*)((char*)Bs + q * 4096 + wave * 1024);
                    gload_lds16(bbase + (size_t)row * D_ + kb * 64 + (col2 >> 1), ldstb);
                }
                __syncthreads();
#pragma unroll
                for (int ks = 0; ks < 2; ++ks) {
                    half8 af[2];
#pragma unroll
                    for (int rt = 0; rt < 2; ++rt) {
                        int row = wave * 32 + rt * 16 + l15;
                        int c2  = (ks * 64 + quad * 16) ^ ((row & 7) << 4);
                        af[rt] = *(const half8*)&As[row * 64 + (c2 >> 1)];
                    }
#pragma unroll
                    for (int ct = 0; ct < 8; ++ct) {
                        int brw = ct * 16 + l15;
                        int c2  = (ks * 64 + quad * 16) ^ ((brw & 7) << 4);
                        half8 bf = *(const half8*)&Bs[brw * 64 + (c2 >> 1)];
                        acc[0][ct] = __builtin_amdgcn_mfma_f32_16x16x32_f16(af[0], bf, acc[0][ct], 0, 0, 0);
                        acc[1][ct] = __builtin_amdgcn_mfma_f32_16x16x32_f16(af[1], bf, acc[1][ct], 0, 0, 0);
                    }
                }
            }
#pragma unroll
            for (int ct = 0; ct < 8; ++ct) {
                int col = n0 + ct * 16 + l15;
                float bs = bias[col];
#pragma unroll
                for (int rt = 0; rt < 2; ++rt)
#pragma unroll
                    for (int r = 0; r < 4; ++r) {
                        int tt = tb + wave * 32 + rt * 16 + quad * 4 + r;   // absolute t
                        xw[((size_t)tt * B_ + b) * G4H + col] = (_Float16)(acc[rt][ct][r] + bs);
                    }
            }
            __syncthreads();   // drains vmcnt: all tile stores complete (in L2)
            if (tid == 0)      // release: L2 writeback -> xw agent-visible, then count
                __hip_atomic_fetch_add(&ctrl[16 + 16 * chunk], 1u,
                                       __ATOMIC_RELEASE, __HIP_MEMORY_SCOPE_AGENT);
        }
        return;
    }

    // ================= scan role: VERBATIM r5 (absolute t, chunk gate) =================
    const int w    = blockIdx.x;
    const int g    = w & 3;
    const int s    = w >> 2;
    const int u0   = s * 32;
    const int gt   = wave;            // wave v = gate v (r5)

    half8 bfrag[2][16];
#pragma unroll
    for (int ct = 0; ct < 2; ++ct) {
        const int col = gt * H_ + u0 + ct * 16 + l15;
        const _Float16* wp = WrT + (size_t)col * D_;
#pragma unroll
        for (int kt = 0; kt < 16; ++kt)
            bfrag[ct][kt] = *(const half8*)(wp + kt * 32 + quad * 8);
    }

    const int rho  = tid >> 4;        // batch-row in group
    const int jj   = tid & 15;        // unit-pair in slice
    const int brow = g * 16 + rho;
    const int un0  = u0 + 2 * jj;     // this thread's two units
    float c0 = 0.f, c1 = 0.f;

    const size_t slotSz = (size_t)B_ * H_;   // dwords per slot

    for (int t = 0; t < T_; ++t) {
        // chunk gate: once per 128 steps, wait for xw chunk then acquire
        if ((t & 127) == 0) {
            if (tid == 0) {
                int gd = 0;
                while (__hip_atomic_load(&ctrl[16 + 16 * (t >> 7)], __ATOMIC_RELAXED,
                                         __HIP_MEMORY_SCOPE_AGENT) < TILES_PER_CHUNK
                       && ++gd < (1 << 20)) {}
            }
            __syncthreads();
            __builtin_amdgcn_fence(__ATOMIC_ACQUIRE, "agent");   // inv L1/L2: see xw
        }

        // prefetch xw: 4 plain f16-pair dwords, one per gate (absolute t)
        const unsigned* xwd = (const unsigned*)(xw + ((size_t)t * B_ + brow) * G4H);
        const int dbase = (u0 >> 1) + jj;
        unsigned xwi = xwd[0 * 256 + dbase];
        unsigned xwf = xwd[1 * 256 + dbase];
        unsigned xwg = xwd[2 * 256 + dbase];
        unsigned xwo = xwd[3 * 256 + dbase];

        if (t > 0) {
            // poll tagged h data: thread covers units 2*tid,2*tid+1 for all 16 rows
            const ull* src = (const ull*)(hbuf + (size_t)((t - 1) % 3) * slotSz)
                             + (size_t)(g * 16) * 256 + tid;
            const unsigned tgt = (unsigned)(t & 0xffff);
            const ull expect = ((ull)tgt << 16) | ((ull)tgt << 48);
            ull v[16];
            int guard = 0;
            while (true) {
                ull diff = 0;
#pragma unroll
                for (int k = 0; k < 16; ++k)
                    v[k] = __hip_atomic_load(src + (size_t)k * 256,
                                             __ATOMIC_RELAXED, __HIP_MEMORY_SCOPE_AGENT);
#pragma unroll
                for (int k = 0; k < 16; ++k)
                    diff |= (v[k] ^ expect) & 0xffff0000ffff0000ull;
                if (diff == 0) break;
                if (++guard > 8192) break;   // bailout: visible failure, not a hang
            }
#pragma unroll
            for (int k = 0; k < 16; ++k) {
                unsigned pk = (unsigned)(v[k] & 0xffffu) | (((unsigned)(v[k] >> 32)) << 16);
                *(unsigned*)&hS[k][2 * tid] = pk;
            }
        }
        __syncthreads();   // BARRIER1: hS staged (also protects hS vs prev-step readers)

        f32x4 a0 = {0.f,0.f,0.f,0.f}, a1 = a0, b0 = a0, b1 = a0;
        if (t > 0) {
#pragma unroll
            for (int kt = 0; kt < 16; kt += 2) {
                half8 af0 = *(const half8*)&hS[l15][kt * 32 + quad * 8];
                half8 af1 = *(const half8*)&hS[l15][(kt + 1) * 32 + quad * 8];
                a0 = __builtin_amdgcn_mfma_f32_16x16x32_f16(af0, bfrag[0][kt],     a0, 0, 0, 0);
                a1 = __builtin_amdgcn_mfma_f32_16x16x32_f16(af0, bfrag[1][kt],     a1, 0, 0, 0);
                b0 = __builtin_amdgcn_mfma_f32_16x16x32_f16(af1, bfrag[0][kt + 1], b0, 0, 0, 0);
                b1 = __builtin_amdgcn_mfma_f32_16x16x32_f16(af1, bfrag[1][kt + 1], b1, 0, 0, 0);
            }
        }
        f32x4 z0 = a0 + b0, z1 = a1 + b1;
#pragma unroll
        for (int r = 0; r < 4; ++r) {
            zS[quad * 4 + r][gt][l15]      = z0[r];
            zS[quad * 4 + r][gt][16 + l15] = z1[r];
        }
        __syncthreads();   // BARRIER2: zS ready

        float zi0 = zS[rho][0][2*jj] + lo16f(xwi), zi1 = zS[rho][0][2*jj+1] + hi16f(xwi);
        float zf0 = zS[rho][1][2*jj] + lo16f(xwf), zf1 = zS[rho][1][2*jj+1] + hi16f(xwf);
        float zg0 = zS[rho][2][2*jj] + lo16f(xwg), zg1 = zS[rho][2][2*jj+1] + hi16f(xwg);
        float zo0 = zS[rho][3][2*jj] + lo16f(xwo), zo1 = zS[rho][3][2*jj+1] + hi16f(xwo);

        c0 = sigm(zf0) * c0 + sigm(zi0) * tanh_(zg0);
        c1 = sigm(zf1) * c1 + sigm(zi1) * tanh_(zg1);
        float h0 = sigm(zo0) * tanh_(c0);
        float h1 = sigm(zo1) * tanh_(c1);

        // tagged publish: ONE 8B relaxed agent store (proven protocol)
        const unsigned tagw = ((unsigned)((t + 1) & 0xffff)) << 16;
        unsigned d0 = (unsigned)__builtin_bit_cast(unsigned short, (_Float16)h0) | tagw;
        unsigned d1 = (unsigned)__builtin_bit_cast(unsigned short, (_Float16)h1) | tagw;
        ull wv = (ull)d0 | ((ull)d1 << 32);
        __hip_atomic_store((ull*)(hbuf + (size_t)(t % 3) * slotSz) + (size_t)brow * 256 + (un0 >> 1),
                           wv, __ATOMIC_RELAXED, __HIP_MEMORY_SCOPE_AGENT);

        if (t == T_ - 1) {
            out[(size_t)brow * H_ + un0]     = h0;
            out[(size_t)brow * H_ + un0 + 1] = h1;
        }
    }
}

// ---------------- fallback (small ws): r5 chunked kernels, verbatim ----------------
__global__ __launch_bounds__(256) void gemm_xw_small(const float* __restrict__ x,
                                                     const _Float16* __restrict__ WkT,
                                                     const float* __restrict__ bias,
                                                     _Float16* __restrict__ xw,
                                                     int tbase) {
    __shared__ _Float16 As[64][40];
    __shared__ _Float16 Bst[64][40];
    const int tid  = threadIdx.x;
    const int lane = tid & 63;
    const int wave = tid >> 6;
    const int l15  = lane & 15;
    const int quad = lane >> 4;
    const int b     = blockIdx.z;
    const int n0    = blockIdx.x * 64;
    const int tloc0 = blockIdx.y * 64;

    const float* xbase = x + ((size_t)b * T_ + (tbase + tloc0)) * D_;
    f32x4 acc[4];
#pragma unroll
    for (int i = 0; i < 4; ++i) acc[i] = (f32x4){0.f, 0.f, 0.f, 0.f};
    const int ai = tid >> 2, ac = tid & 3;
    const int bn = tid >> 2, bq = tid & 3;

    for (int kb = 0; kb < 16; ++kb) {
        __syncthreads();
        const float* ap = xbase + (size_t)ai * D_ + kb * 32 + ac * 8;
        f32x4 av0 = *(const f32x4*)ap;
        f32x4 av1 = *(const f32x4*)(ap + 4);
        half8 ah = { (_Float16)av0.x, (_Float16)av0.y, (_Float16)av0.z, (_Float16)av0.w,
                     (_Float16)av1.x, (_Float16)av1.y, (_Float16)av1.z, (_Float16)av1.w };
        *(half8*)&As[ai][ac * 8] = ah;
        half8 bv = *(const half8*)(WkT + (size_t)(n0 + bn) * D_ + kb * 32 + bq * 8);
        *(half8*)&Bst[bn][bq * 8] = bv;
        __syncthreads();

        half8 afrag = *(const half8*)&As[16 * wave + l15][quad * 8];
#pragma unroll
        for (int nt = 0; nt < 4; ++nt) {
            half8 bfrag = *(const half8*)&Bst[nt * 16 + l15][quad * 8];
            acc[nt] = __builtin_amdgcn_mfma_f32_16x16x32_f16(afrag, bfrag, acc[nt], 0, 0, 0);
        }
    }
#pragma unroll
    for (int nt = 0; nt < 4; ++nt)
#pragma unroll
        for (int r = 0; r < 4; ++r) {
            int tt  = tloc0 + 16 * wave + quad * 4 + r;
            int col = n0 + nt * 16 + l15;
            xw[((size_t)tt * B_ + b) * G4H + col] = (_Float16)(acc[nt][r] + bias[col]);
        }
}

__global__ __launch_bounds__(256, 1) void lstm_scan(const _Float16* __restrict__ xw,
                                                    const _Float16* __restrict__ WrT,
                                                    unsigned* __restrict__ hbuf,
                                                    float* __restrict__ cio,
                                                    float* __restrict__ out,
                                                    int t0, int t1) {
    const int w    = blockIdx.x;
    const int g    = w & 3;
    const int s    = w >> 2;
    const int u0   = s * 32;
    const int tid  = threadIdx.x;
    const int lane = tid & 63;
    const int wave = tid >> 6;
    const int l15  = lane & 15;
    const int quad = lane >> 4;

    half8 bfrag[2][16];
#pragma unroll
    for (int ct = 0; ct < 2; ++ct) {
        const int col = wave * H_ + u0 + ct * 16 + l15;
        const _Float16* wp = WrT + (size_t)col * D_;
#pragma unroll
        for (int kt = 0; kt < 16; ++kt)
            bfrag[ct][kt] = *(const half8*)(wp + kt * 32 + quad * 8);
    }

    const int rho  = tid >> 4;
    const int jj   = tid & 15;
    const int brow = g * 16 + rho;
    const int un0  = u0 + 2 * jj;
    float c0 = 0.f, c1 = 0.f;
    if (t0 != 0) {
        c0 = cio[(size_t)brow * H_ + un0];
        c1 = cio[(size_t)brow * H_ + un0 + 1];
    }

    __shared__ _Float16 hS[16][520];
    __shared__ float    zS[16][4][34];
    const size_t slotSz = (size_t)B_ * H_;

    for (int t = t0; t < t1; ++t) {
        const unsigned* xwd = (const unsigned*)(xw + ((size_t)(t - t0) * B_ + brow) * G4H);
        const int dbase = (u0 >> 1) + jj;
        unsigned xwi = xwd[0 * 256 + dbase];
        unsigned xwf = xwd[1 * 256 + dbase];
        unsigned xwg = xwd[2 * 256 + dbase];
        unsigned xwo = xwd[3 * 256 + dbase];

        if (t > 0) {
            const ull* src = (const ull*)(hbuf + (size_t)((t - 1) % 3) * slotSz)
                             + (size_t)(g * 16) * 256 + tid;
            const unsigned tgt = (unsigned)(t & 0xffff);
            const ull expect = ((ull)tgt << 16) | ((ull)tgt << 48);
            ull v[16];
            int guard = 0;
            while (true) {
                ull diff = 0;
#pragma unroll
                for (int k = 0; k < 16; ++k)
                    v[k] = __hip_atomic_load(src + (size_t)k * 256,
                                             __ATOMIC_RELAXED, __HIP_MEMORY_SCOPE_AGENT);
#pragma unroll
                for (int k = 0; k < 16; ++k)
                    diff |= (v[k] ^ expect) & 0xffff0000ffff0000ull;
                if (diff == 0) break;
                if (++guard > 8192) break;
            }
#pragma unroll
            for (int k = 0; k < 16; ++k) {
                unsigned p = (unsigned)(v[k] & 0xffffu) | (((unsigned)(v[k] >> 32)) << 16);
                *(unsigned*)&hS[k][2 * tid] = p;
            }
        }
        __syncthreads();

        f32x4 a0 = {0.f,0.f,0.f,0.f}, a1 = a0, b0 = a0, b1 = a0;
        if (t > 0) {
#pragma unroll
            for (int kt = 0; kt < 16; kt += 2) {
                half8 af0 = *(const half8*)&hS[l15][kt * 32 + quad * 8];
                half8 af1 = *(const half8*)&hS[l15][(kt + 1) * 32 + quad * 8];
                a0 = __builtin_amdgcn_mfma_f32_16x16x32_f16(af0, bfrag[0][kt],     a0, 0, 0, 0);
                a1 = __builtin_amdgcn_mfma_f32_16x16x32_f16(af0, bfrag[1][kt],     a1, 0, 0, 0);
                b0 = __builtin_amdgcn_mfma_f32_16x16x32_f16(af1, bfrag[0][kt + 1], b0, 0, 0, 0);
                b1 = __builtin_amdgcn_mfma_f32_16x16x32_f16(af1, bfrag[1][kt + 1], b1, 0, 0, 0);
            }
        }
        f32x4 z0 = a0 + b0, z1 = a1 + b1;
#pragma unroll
        for (int r = 0; r < 4; ++r) {
            zS[quad * 4 + r][wave][l15]      = z0[r];
            zS[quad * 4 + r][wave][16 + l15] = z1[r];
        }
        __syncthreads();

        float zi0 = zS[rho][0][2*jj] + lo16f(xwi), zi1 = zS[rho][0][2*jj+1] + hi16f(xwi);
        float zf0 = zS[rho][1][2*jj] + lo16f(xwf), zf1 = zS[rho][1][2*jj+1] + hi16f(xwf);
        float zg0 = zS[rho][2][2*jj] + lo16f(xwg), zg1 = zS[rho][2][2*jj+1] + hi16f(xwg);
        float zo0 = zS[rho][3][2*jj] + lo16f(xwo), zo1 = zS[rho][3][2*jj+1] + hi16f(xwo);

        c0 = sigm(zf0) * c0 + sigm(zi0) * tanh_(zg0);
        c1 = sigm(zf1) * c1 + sigm(zi1) * tanh_(zg1);
        float h0 = sigm(zo0) * tanh_(c0);
        float h1 = sigm(zo1) * tanh_(c1);

        const unsigned tagw = ((unsigned)((t + 1) & 0xffff)) << 16;
        unsigned d0 = (unsigned)__builtin_bit_cast(unsigned short, (_Float16)h0) | tagw;
        unsigned d1 = (unsigned)__builtin_bit_cast(unsigned short, (_Float16)h1) | tagw;
        ull wv = (ull)d0 | ((ull)d1 << 32);
        __hip_atomic_store((ull*)(hbuf + (size_t)(t % 3) * slotSz) + (size_t)brow * 256 + (un0 >> 1),
                           wv, __ATOMIC_RELAXED, __HIP_MEMORY_SCOPE_AGENT);

        if (t == T_ - 1) {
            out[(size_t)brow * H_ + un0]     = h0;
            out[(size_t)brow * H_ + un0 + 1] = h1;
        }
    }
    cio[(size_t)brow * H_ + un0]     = c0;
    cio[(size_t)brow * H_ + un0 + 1] = c1;
}

// ---------------- launch
extern "C" void kernel_launch(void* const* d_in, const int* in_sizes, int n_in,
                              void* d_out, int out_size, void* d_ws, size_t ws_size,
                              hipStream_t stream) {
    (void)in_sizes; (void)n_in;
    const float* x    = (const float*)d_in[0];
    const float* Wk   = (const float*)d_in[1];
    const float* Wr   = (const float*)d_in[2];
    const float* bias = (const float*)d_in[3];
    float* out = (float*)d_out;

    char* ws = (char*)d_ws;
    _Float16* WkT  = (_Float16*)(ws + 1024);                      // 2 MB
    _Float16* WrT  = (_Float16*)(ws + 1024 + 2097152);            // 2 MB
    unsigned* hbuf = (unsigned*)(ws + 1024 + 2 * 2097152);        // 384 KB (3 slots)
    float*    cio  = (float*)(ws + 1024 + 2 * 2097152 + 393216);  // 128 KB (ctrl in fused)
    unsigned* ctrl = (unsigned*)cio;
    const size_t fixed   = 1024 + 2 * 2097152 + 393216 + 131072;
    const size_t xhBytes = (size_t)B_ * T_ * D_ * 2;              // 64 MB
    const size_t perT    = (size_t)B_ * G4H * 2;                  // 256 KB per timestep

    size_t avail = (ws_size > fixed) ? ws_size - fixed : 0;
    _Float16* xh = (_Float16*)(ws + fixed);
    bool fused_ok = avail >= xhBytes + (size_t)T_ * perT;         // 64 + 256 MB

    if (fused_ok) {
        _Float16* xw = (_Float16*)(ws + fixed + xhBytes);
        // zero hbuf (98304 dwords) + ctrl (contiguous right after) in one pass
        zero_buf<<<96, 256, 0, stream>>>(hbuf, 3 * B_ * H_ + 256);
        trans_w<<<512, 256, 0, stream>>>(Wk, WkT);
        trans_w<<<512, 256, 0, stream>>>(Wr, WrT);
        conv_x<<<2048, 256, 0, stream>>>(x, xh);
        lstm_fused<<<64 + NPROD, 256, 0, stream>>>(xh, WkT, bias, xw, WrT, hbuf, out, ctrl);
        return;
    }

    // -------- fallback: r5 chunked path (f32 x, small gemm) --------
    _Float16* xw = (_Float16*)(ws + fixed);
    int ct = 0;
    const int cands[5] = {1024, 512, 256, 128, 64};
    for (int i = 0; i < 5; ++i)
        if ((size_t)cands[i] * perT <= avail) { ct = cands[i]; break; }
    if (ct == 0) {
        hipMemsetAsync(d_out, 0, (size_t)out_size * 4, stream);
        return;
    }
    zero_buf<<<96, 256, 0, stream>>>(hbuf, 3 * B_ * H_);
    trans_w<<<512, 256, 0, stream>>>(Wk, WkT);
    trans_w<<<512, 256, 0, stream>>>(Wr, WrT);
    for (int t0 = 0; t0 < T_; t0 += ct) {
        gemm_xw_small<<<dim3(32, ct / 64, B_), 256, 0, stream>>>(x, WkT, bias, xw, t0);
        lstm_scan<<<64, 256, 0, stream>>>(xw, WrT, hbuf, cio, out, t0, t0 + ct);
    }
}